// Round 1
// baseline (673.233 us; speedup 1.0000x reference)
//
#include <hip/hip_runtime.h>
#include <hip/hip_bf16.h>
#include <math.h>

#define B_   32
#define S_   512
#define SxS  (S_ * S_)
#define LOG2E 1.4426950408889634f

// ---------------------------------------------------------------------------
// Kernel 1: e[b,i,j] = sum_d A[b,i,d] * B[b,j,d]   (A·B^T, both K-contiguous)
// 64x64 output tile, BK=16, 256 threads, 4x4 micro-tile per thread.
// ---------------------------------------------------------------------------
__global__ __launch_bounds__(256) void k_gemm_e(const float* __restrict__ A,
                                                const float* __restrict__ Bm,
                                                float* __restrict__ E)
{
    const int b  = blockIdx.z;
    const int i0 = blockIdx.y * 64;
    const int j0 = blockIdx.x * 64;
    const float* Ab = A  + (size_t)b * SxS;
    const float* Bb = Bm + (size_t)b * SxS;
    float*       Eb = E  + (size_t)b * SxS;

    __shared__ float As[16][64];   // As[k][i]
    __shared__ float Bs[16][64];   // Bs[k][j]

    const int tid  = threadIdx.x;
    const int lrow = tid >> 2;          // 0..63 : tile row being loaded
    const int lk   = (tid & 3) << 2;    // 0,4,8,12 : k offset (float4)
    const int ty   = tid >> 4;          // 0..15 : output row group
    const int tx   = tid & 15;          // 0..15 : output col group

    float acc[4][4] = {};

    for (int k0 = 0; k0 < S_; k0 += 16) {
        float4 av = *(const float4*)(Ab + (size_t)(i0 + lrow) * S_ + k0 + lk);
        float4 bv = *(const float4*)(Bb + (size_t)(j0 + lrow) * S_ + k0 + lk);
        __syncthreads();
        As[lk + 0][lrow] = av.x; As[lk + 1][lrow] = av.y;
        As[lk + 2][lrow] = av.z; As[lk + 3][lrow] = av.w;
        Bs[lk + 0][lrow] = bv.x; Bs[lk + 1][lrow] = bv.y;
        Bs[lk + 2][lrow] = bv.z; Bs[lk + 3][lrow] = bv.w;
        __syncthreads();
        #pragma unroll
        for (int k = 0; k < 16; ++k) {
            const float4 a4 = *(const float4*)&As[k][ty * 4];
            const float4 b4 = *(const float4*)&Bs[k][tx * 4];
            acc[0][0] += a4.x * b4.x; acc[0][1] += a4.x * b4.y;
            acc[0][2] += a4.x * b4.z; acc[0][3] += a4.x * b4.w;
            acc[1][0] += a4.y * b4.x; acc[1][1] += a4.y * b4.y;
            acc[1][2] += a4.y * b4.z; acc[1][3] += a4.y * b4.w;
            acc[2][0] += a4.z * b4.x; acc[2][1] += a4.z * b4.y;
            acc[2][2] += a4.z * b4.z; acc[2][3] += a4.z * b4.w;
            acc[3][0] += a4.w * b4.x; acc[3][1] += a4.w * b4.y;
            acc[3][2] += a4.w * b4.z; acc[3][3] += a4.w * b4.w;
        }
    }
    #pragma unroll
    for (int ii = 0; ii < 4; ++ii) {
        float4 v = make_float4(acc[ii][0], acc[ii][1], acc[ii][2], acc[ii][3]);
        *(float4*)(Eb + (size_t)(i0 + ty * 4 + ii) * S_ + j0 + tx * 4) = v;
    }
}

// ---------------------------------------------------------------------------
// Kernel 2: per-row (over j) max and 1/sum(exp). One wave per row.
// ---------------------------------------------------------------------------
__global__ __launch_bounds__(256) void k_rowstats(const float* __restrict__ E,
                                                  float* __restrict__ rmax,
                                                  float* __restrict__ rinv)
{
    const int row  = blockIdx.x * 4 + (threadIdx.x >> 6);   // [0, 32*512)
    const int lane = threadIdx.x & 63;
    const float* er = E + (size_t)row * S_;

    float4 v0 = *(const float4*)(er + lane * 4);
    float4 v1 = *(const float4*)(er + 256 + lane * 4);

    float m = fmaxf(fmaxf(fmaxf(v0.x, v0.y), fmaxf(v0.z, v0.w)),
                    fmaxf(fmaxf(v1.x, v1.y), fmaxf(v1.z, v1.w)));
    #pragma unroll
    for (int off = 32; off >= 1; off >>= 1)
        m = fmaxf(m, __shfl_xor(m, off));

    float s = exp2f((v0.x - m) * LOG2E) + exp2f((v0.y - m) * LOG2E)
            + exp2f((v0.z - m) * LOG2E) + exp2f((v0.w - m) * LOG2E)
            + exp2f((v1.x - m) * LOG2E) + exp2f((v1.y - m) * LOG2E)
            + exp2f((v1.z - m) * LOG2E) + exp2f((v1.w - m) * LOG2E);
    #pragma unroll
    for (int off = 32; off >= 1; off >>= 1)
        s += __shfl_xor(s, off);

    if (lane == 0) { rmax[row] = m; rinv[row] = 1.0f / s; }
}

// ---------------------------------------------------------------------------
// Kernel 3: per-column (over i) max and 1/sum(exp). Online softmax, coalesced.
// block = 256 (4 partials x 64 columns); grid = (8 col-tiles, 32 batches)
// ---------------------------------------------------------------------------
__global__ __launch_bounds__(256) void k_colstats(const float* __restrict__ E,
                                                  float* __restrict__ cmax,
                                                  float* __restrict__ cinv)
{
    const int b    = blockIdx.y;
    const int lane = threadIdx.x & 63;
    const int ty   = threadIdx.x >> 6;      // 0..3
    const int j    = blockIdx.x * 64 + lane;
    const float* Eb = E + (size_t)b * SxS;

    float m = -INFINITY, s = 0.0f;
    for (int i = ty; i < S_; i += 4) {
        float x  = Eb[(size_t)i * S_ + j];
        float nm = fmaxf(m, x);
        s = s * exp2f((m - nm) * LOG2E) + exp2f((x - nm) * LOG2E);
        m = nm;
    }

    __shared__ float sm[4][64];
    __shared__ float ss[4][64];
    sm[ty][lane] = m; ss[ty][lane] = s;
    __syncthreads();

    if (ty == 0) {
        float M = m, Ssum = s;
        #pragma unroll
        for (int t = 1; t < 4; ++t) {
            float m2 = sm[t][lane], s2 = ss[t][lane];
            float nm = fmaxf(M, m2);
            Ssum = Ssum * exp2f((M - nm) * LOG2E) + s2 * exp2f((m2 - nm) * LOG2E);
            M = nm;
        }
        cmax[b * S_ + j] = M;
        cinv[b * S_ + j] = 1.0f / Ssum;
    }
}

// ---------------------------------------------------------------------------
// Kernel 4: a_tilde = softmax_row(e) · B, fused m_a concat write.
// out tile [i:64][d:64]; K = j. P computed on the fly: exp(e - rmax[i]),
// 1/rsum folded into the epilogue.
// ---------------------------------------------------------------------------
__global__ __launch_bounds__(256) void k_ma(const float* __restrict__ A,
                                            const float* __restrict__ Bm,
                                            const float* __restrict__ E,
                                            const float* __restrict__ rmax,
                                            const float* __restrict__ rinv,
                                            float* __restrict__ Ma)
{
    const int b  = blockIdx.z;
    const int i0 = blockIdx.y * 64;
    const int d0 = blockIdx.x * 64;
    const float* Ab = A  + (size_t)b * SxS;
    const float* Bb = Bm + (size_t)b * SxS;
    const float* Eb = E  + (size_t)b * SxS;
    const float* rm = rmax + b * S_;
    const float* ri = rinv + b * S_;
    float* Mab = Ma + (size_t)b * S_ * 2048;

    __shared__ float Ps[16][64];   // Ps[k][i]
    __shared__ float Bs[16][64];   // Bs[k][d]

    const int tid  = threadIdx.x;
    const int lrow = tid >> 2;          // P loader: i row 0..63
    const int lk   = (tid & 3) << 2;    // P loader: j(k) offset
    const int nrow = tid >> 4;          // B loader: j(k) row 0..15
    const int nc   = (tid & 15) << 2;   // B loader: d offset
    const int ty   = tid >> 4;
    const int tx   = tid & 15;

    const float rml = rm[i0 + lrow];
    float acc[4][4] = {};

    for (int k0 = 0; k0 < S_; k0 += 16) {
        float4 ev = *(const float4*)(Eb + (size_t)(i0 + lrow) * S_ + k0 + lk);
        float4 bv = *(const float4*)(Bb + (size_t)(k0 + nrow) * S_ + d0 + nc);
        float4 pv;
        pv.x = exp2f((ev.x - rml) * LOG2E);
        pv.y = exp2f((ev.y - rml) * LOG2E);
        pv.z = exp2f((ev.z - rml) * LOG2E);
        pv.w = exp2f((ev.w - rml) * LOG2E);
        __syncthreads();
        Ps[lk + 0][lrow] = pv.x; Ps[lk + 1][lrow] = pv.y;
        Ps[lk + 2][lrow] = pv.z; Ps[lk + 3][lrow] = pv.w;
        *(float4*)&Bs[nrow][nc] = bv;
        __syncthreads();
        #pragma unroll
        for (int k = 0; k < 16; ++k) {
            const float4 a4 = *(const float4*)&Ps[k][ty * 4];
            const float4 b4 = *(const float4*)&Bs[k][tx * 4];
            acc[0][0] += a4.x * b4.x; acc[0][1] += a4.x * b4.y;
            acc[0][2] += a4.x * b4.z; acc[0][3] += a4.x * b4.w;
            acc[1][0] += a4.y * b4.x; acc[1][1] += a4.y * b4.y;
            acc[1][2] += a4.y * b4.z; acc[1][3] += a4.y * b4.w;
            acc[2][0] += a4.z * b4.x; acc[2][1] += a4.z * b4.y;
            acc[2][2] += a4.z * b4.z; acc[2][3] += a4.z * b4.w;
            acc[3][0] += a4.w * b4.x; acc[3][1] += a4.w * b4.y;
            acc[3][2] += a4.w * b4.z; acc[3][3] += a4.w * b4.w;
        }
    }

    #pragma unroll
    for (int ii = 0; ii < 4; ++ii) {
        const int i = i0 + ty * 4 + ii;
        const float s = ri[i];
        float4 at = make_float4(acc[ii][0] * s, acc[ii][1] * s,
                                acc[ii][2] * s, acc[ii][3] * s);
        float4 av = *(const float4*)(Ab + (size_t)i * S_ + d0 + tx * 4);
        float* row = Mab + (size_t)i * 2048 + d0 + tx * 4;
        *(float4*)(row)        = av;
        *(float4*)(row + 512)  = at;
        *(float4*)(row + 1024) = make_float4(av.x - at.x, av.y - at.y,
                                             av.z - at.z, av.w - at.w);
        *(float4*)(row + 1536) = make_float4(av.x * at.x, av.y * at.y,
                                             av.z * at.z, av.w * at.w);
    }
}

// ---------------------------------------------------------------------------
// Kernel 5: b_tilde[j,d] = sum_i softmax_col(e)[i,j] * A[i,d], fused m_b write.
// out tile [j:64][d:64]; K = i. Both loaders are natural layout.
// ---------------------------------------------------------------------------
__global__ __launch_bounds__(256) void k_mb(const float* __restrict__ A,
                                            const float* __restrict__ Bm,
                                            const float* __restrict__ E,
                                            const float* __restrict__ cmax,
                                            const float* __restrict__ cinv,
                                            float* __restrict__ Mb)
{
    const int b  = blockIdx.z;
    const int j0 = blockIdx.y * 64;
    const int d0 = blockIdx.x * 64;
    const float* Ab = A  + (size_t)b * SxS;
    const float* Bb = Bm + (size_t)b * SxS;
    const float* Eb = E  + (size_t)b * SxS;
    const float* cm = cmax + b * S_;
    const float* ci = cinv + b * S_;
    float* Mbb = Mb + (size_t)b * S_ * 2048;

    __shared__ float Ps[16][64];   // Ps[k=i][j]
    __shared__ float As[16][64];   // As[k=i][d]

    const int tid  = threadIdx.x;
    const int nrow = tid >> 4;          // i row 0..15
    const int nc   = (tid & 15) << 2;   // col offset (j for P, d for A)
    const int ty   = tid >> 4;
    const int tx   = tid & 15;

    const float4 cm4 = *(const float4*)(cm + j0 + nc);
    float acc[4][4] = {};

    for (int k0 = 0; k0 < S_; k0 += 16) {
        float4 ev = *(const float4*)(Eb + (size_t)(k0 + nrow) * S_ + j0 + nc);
        float4 av = *(const float4*)(Ab + (size_t)(k0 + nrow) * S_ + d0 + nc);
        float4 pv;
        pv.x = exp2f((ev.x - cm4.x) * LOG2E);
        pv.y = exp2f((ev.y - cm4.y) * LOG2E);
        pv.z = exp2f((ev.z - cm4.z) * LOG2E);
        pv.w = exp2f((ev.w - cm4.w) * LOG2E);
        __syncthreads();
        *(float4*)&Ps[nrow][nc] = pv;
        *(float4*)&As[nrow][nc] = av;
        __syncthreads();
        #pragma unroll
        for (int k = 0; k < 16; ++k) {
            const float4 p4 = *(const float4*)&Ps[k][ty * 4];
            const float4 a4 = *(const float4*)&As[k][tx * 4];
            acc[0][0] += p4.x * a4.x; acc[0][1] += p4.x * a4.y;
            acc[0][2] += p4.x * a4.z; acc[0][3] += p4.x * a4.w;
            acc[1][0] += p4.y * a4.x; acc[1][1] += p4.y * a4.y;
            acc[1][2] += p4.y * a4.z; acc[1][3] += p4.y * a4.w;
            acc[2][0] += p4.z * a4.x; acc[2][1] += p4.z * a4.y;
            acc[2][2] += p4.z * a4.z; acc[2][3] += p4.z * a4.w;
            acc[3][0] += p4.w * a4.x; acc[3][1] += p4.w * a4.y;
            acc[3][2] += p4.w * a4.z; acc[3][3] += p4.w * a4.w;
        }
    }

    #pragma unroll
    for (int jj = 0; jj < 4; ++jj) {
        const int j = j0 + ty * 4 + jj;
        const float s = ci[j];
        float4 bt = make_float4(acc[jj][0] * s, acc[jj][1] * s,
                                acc[jj][2] * s, acc[jj][3] * s);
        float4 bv = *(const float4*)(Bb + (size_t)j * S_ + d0 + tx * 4);
        float* row = Mbb + (size_t)j * 2048 + d0 + tx * 4;
        *(float4*)(row)        = bv;
        *(float4*)(row + 512)  = bt;
        *(float4*)(row + 1024) = make_float4(bv.x - bt.x, bv.y - bt.y,
                                             bv.z - bt.z, bv.w - bt.w);
        *(float4*)(row + 1536) = make_float4(bv.x * bt.x, bv.y * bt.y,
                                             bv.z * bt.z, bv.w * bt.w);
    }
}

// ---------------------------------------------------------------------------
extern "C" void kernel_launch(void* const* d_in, const int* in_sizes, int n_in,
                              void* d_out, int out_size, void* d_ws, size_t ws_size,
                              hipStream_t stream)
{
    const float* A  = (const float*)d_in[0];   // a_bar [32,512,512]
    const float* Bm = (const float*)d_in[1];   // b_bar [32,512,512]
    float* Ma = (float*)d_out;                             // [32,512,2048]
    float* Mb = Ma + (size_t)B_ * S_ * 2048;               // [32,512,2048]

    // workspace layout: e (33.55 MB) + 4 stat vectors (64 KB each)
    float* E    = (float*)d_ws;
    float* rmax = E + (size_t)B_ * SxS;
    float* rinv = rmax + B_ * S_;
    float* cmax = rinv + B_ * S_;
    float* cinv = cmax + B_ * S_;

    k_gemm_e  <<<dim3(8, 8, B_),        256, 0, stream>>>(A, Bm, E);
    k_rowstats<<<dim3(B_ * S_ / 4),     256, 0, stream>>>(E, rmax, rinv);
    k_colstats<<<dim3(8, B_),           256, 0, stream>>>(E, cmax, cinv);
    k_ma      <<<dim3(8, 8, B_),        256, 0, stream>>>(A, Bm, E, rmax, rinv, Ma);
    k_mb      <<<dim3(8, 8, B_),        256, 0, stream>>>(A, Bm, E, cmax, cinv, Mb);
}

// Round 2
// 469.792 us; speedup vs baseline: 1.4330x; 1.4330x over previous
//
#include <hip/hip_runtime.h>
#include <hip/hip_bf16.h>
#include <math.h>

#define B_   32
#define S_   512
#define SxS  (S_ * S_)
#define LOG2E 1.4426950408889634f

using frag_ab = __attribute__((ext_vector_type(8))) short;   // 8 bf16 = 4 VGPR
using frag_cd = __attribute__((ext_vector_type(4))) float;   // 4 fp32 acc

__device__ inline short f2bf(float x) {
    __hip_bfloat16 h = __float2bfloat16(x);
    return *reinterpret_cast<short*>(&h);
}
__device__ inline float bf2f(short s) {
    __hip_bfloat16 h = *reinterpret_cast<__hip_bfloat16*>(&s);
    return __bfloat162float(h);
}
__device__ inline void split4(const float4 v, short4& h, short4& l) {
    h.x = f2bf(v.x); l.x = f2bf(v.x - bf2f(h.x));
    h.y = f2bf(v.y); l.y = f2bf(v.y - bf2f(h.y));
    h.z = f2bf(v.z); l.z = f2bf(v.z - bf2f(h.z));
    h.w = f2bf(v.w); l.w = f2bf(v.w - bf2f(h.w));
}

// ---------------------------------------------------------------------------
// Transpose A,B -> bf16 At[d][i], Bt[d][j] (the K-contig V-operand for k_pv).
// ---------------------------------------------------------------------------
__global__ __launch_bounds__(256) void k_trans(const float* __restrict__ A,
                                               const float* __restrict__ Bm,
                                               short* __restrict__ At,
                                               short* __restrict__ Bt)
{
    const int z = blockIdx.z;
    const int b = z & 31;
    const float* X = (z >> 5) ? Bm : A;
    short*     Xt = (z >> 5) ? Bt : At;
    X  += (size_t)b * SxS;
    Xt += (size_t)b * SxS;
    const int i0 = blockIdx.y * 64, d0 = blockIdx.x * 64;

    __shared__ short T[64][68];    // [d_local][i_local], pitch 68 (8B-aligned rows)
    const int r = threadIdx.x >> 4, c = threadIdx.x & 15;

    #pragma unroll
    for (int p = 0; p < 4; ++p) {
        const int i = r + p * 16;
        float4 v = *(const float4*)(X + (size_t)(i0 + i) * S_ + d0 + c * 4);
        T[c * 4 + 0][i] = f2bf(v.x);
        T[c * 4 + 1][i] = f2bf(v.y);
        T[c * 4 + 2][i] = f2bf(v.z);
        T[c * 4 + 3][i] = f2bf(v.w);
    }
    __syncthreads();
    #pragma unroll
    for (int p = 0; p < 4; ++p) {
        const int d = r + p * 16;
        *(short4*)(Xt + (size_t)(d0 + d) * S_ + i0 + c * 4) = *(short4*)&T[d][c * 4];
    }
}

// ---------------------------------------------------------------------------
// e = A·B^T via hi/lo bf16 MFMA (3 products, ~fp32 precision).
// 128x128 tile, BK=32, 4 waves (each one 64x64 quadrant of 16x16 MFMA tiles).
// Writes E[i][j] and Et[j][i] (fp32).
// ---------------------------------------------------------------------------
__global__ __launch_bounds__(256) void k_gemm_e(const float* __restrict__ A,
                                                const float* __restrict__ Bm,
                                                float* __restrict__ E,
                                                float* __restrict__ Et)
{
    const int b  = blockIdx.z;
    const int i0 = blockIdx.y * 128, j0 = blockIdx.x * 128;
    const float* Ab = A  + (size_t)b * SxS;
    const float* Bb = Bm + (size_t)b * SxS;
    float* Eb  = E  + (size_t)b * SxS;
    float* Etb = Et + (size_t)b * SxS;

    __shared__ short Ahi[128][40], Alo[128][40], Bhi[128][40], Blo[128][40]; // 40 KB

    const int tid  = threadIdx.x;
    const int kc   = tid & 7, lr = tid >> 3;     // loader: 8 float4/row, 32 rows/pass
    const int wave = tid >> 6, lane = tid & 63;
    const int wr   = wave >> 1, wc = wave & 1;
    const int q    = lane >> 4, m = lane & 15;

    frag_cd zero = {0.f, 0.f, 0.f, 0.f};
    frag_cd acc[4][4];
    #pragma unroll
    for (int i = 0; i < 4; ++i)
        #pragma unroll
        for (int j = 0; j < 4; ++j) acc[i][j] = zero;

    for (int k0 = 0; k0 < S_; k0 += 32) {
        float4 av[4], bv[4];
        #pragma unroll
        for (int p = 0; p < 4; ++p) {
            av[p] = *(const float4*)(Ab + (size_t)(i0 + lr + 32 * p) * S_ + k0 + kc * 4);
            bv[p] = *(const float4*)(Bb + (size_t)(j0 + lr + 32 * p) * S_ + k0 + kc * 4);
        }
        __syncthreads();
        #pragma unroll
        for (int p = 0; p < 4; ++p) {
            const int rr = lr + 32 * p;
            short4 h4, l4;
            split4(av[p], h4, l4);
            *(short4*)&Ahi[rr][kc * 4] = h4;
            *(short4*)&Alo[rr][kc * 4] = l4;
            split4(bv[p], h4, l4);
            *(short4*)&Bhi[rr][kc * 4] = h4;
            *(short4*)&Blo[rr][kc * 4] = l4;
        }
        __syncthreads();

        frag_ab ah[4], al[4], bh[4], bl[4];
        #pragma unroll
        for (int t = 0; t < 4; ++t) {
            ah[t] = *(const frag_ab*)&Ahi[wr * 64 + t * 16 + m][q * 8];
            al[t] = *(const frag_ab*)&Alo[wr * 64 + t * 16 + m][q * 8];
            bh[t] = *(const frag_ab*)&Bhi[wc * 64 + t * 16 + m][q * 8];
            bl[t] = *(const frag_ab*)&Blo[wc * 64 + t * 16 + m][q * 8];
        }
        #pragma unroll
        for (int mt = 0; mt < 4; ++mt)
            #pragma unroll
            for (int nt = 0; nt < 4; ++nt) {
                acc[mt][nt] = __builtin_amdgcn_mfma_f32_16x16x32_bf16(ah[mt], bh[nt], acc[mt][nt], 0, 0, 0);
                acc[mt][nt] = __builtin_amdgcn_mfma_f32_16x16x32_bf16(ah[mt], bl[nt], acc[mt][nt], 0, 0, 0);
                acc[mt][nt] = __builtin_amdgcn_mfma_f32_16x16x32_bf16(al[mt], bh[nt], acc[mt][nt], 0, 0, 0);
            }
    }

    #pragma unroll
    for (int mt = 0; mt < 4; ++mt)
        #pragma unroll
        for (int nt = 0; nt < 4; ++nt) {
            const int rb  = i0 + wr * 64 + mt * 16 + q * 4;
            const int col = j0 + wc * 64 + nt * 16 + m;
            float4 v = make_float4(acc[mt][nt][0], acc[mt][nt][1],
                                   acc[mt][nt][2], acc[mt][nt][3]);
            Eb[(size_t)(rb + 0) * S_ + col] = v.x;
            Eb[(size_t)(rb + 1) * S_ + col] = v.y;
            Eb[(size_t)(rb + 2) * S_ + col] = v.z;
            Eb[(size_t)(rb + 3) * S_ + col] = v.w;
            *(float4*)(Etb + (size_t)col * S_ + rb) = v;   // transposed copy
        }
}

// ---------------------------------------------------------------------------
// Per-row max and 1/sum(exp) over a [R][512] fp32 matrix. One wave per row.
// ---------------------------------------------------------------------------
__global__ __launch_bounds__(256) void k_rowstats(const float* __restrict__ E,
                                                  float* __restrict__ rmax,
                                                  float* __restrict__ rinv)
{
    const int row  = blockIdx.x * 4 + (threadIdx.x >> 6);
    const int lane = threadIdx.x & 63;
    const float* er = E + (size_t)row * S_;

    float4 v0 = *(const float4*)(er + lane * 4);
    float4 v1 = *(const float4*)(er + 256 + lane * 4);

    float m = fmaxf(fmaxf(fmaxf(v0.x, v0.y), fmaxf(v0.z, v0.w)),
                    fmaxf(fmaxf(v1.x, v1.y), fmaxf(v1.z, v1.w)));
    #pragma unroll
    for (int off = 32; off >= 1; off >>= 1)
        m = fmaxf(m, __shfl_xor(m, off));

    float s = exp2f((v0.x - m) * LOG2E) + exp2f((v0.y - m) * LOG2E)
            + exp2f((v0.z - m) * LOG2E) + exp2f((v0.w - m) * LOG2E)
            + exp2f((v1.x - m) * LOG2E) + exp2f((v1.y - m) * LOG2E)
            + exp2f((v1.z - m) * LOG2E) + exp2f((v1.w - m) * LOG2E);
    #pragma unroll
    for (int off = 32; off >= 1; off >>= 1)
        s += __shfl_xor(s, off);

    if (lane == 0) { rmax[row] = m; rinv[row] = 1.0f / s; }
}

// ---------------------------------------------------------------------------
// out_rows = softmax_row(Es) · V  (V given transposed bf16 [d][k]), fused
// epilogue: scale by rinv, read X fp32, write 4 concat sections.
// 128x128 tile, BK=32, bf16 MFMA. P = exp(Es - rmax) staged on the fly.
// ---------------------------------------------------------------------------
__global__ __launch_bounds__(256) void k_pv(const float* __restrict__ Es,
                                            const float* __restrict__ rmx,
                                            const float* __restrict__ rin,
                                            const short* __restrict__ Vt,
                                            const float* __restrict__ X,
                                            float* __restrict__ Out)
{
    const int b  = blockIdx.z;
    const int r0 = blockIdx.y * 128, d0 = blockIdx.x * 128;
    const float* Eb  = Es + (size_t)b * SxS;
    const short* Vb  = Vt + (size_t)b * SxS;
    const float* Xb  = X  + (size_t)b * SxS;
    const float* rmb = rmx + b * S_;
    const float* rib = rin + b * S_;
    float* Ob = Out + (size_t)b * S_ * 2048;

    __shared__ short Ps[128][40], Vs[128][40];   // 20 KB

    const int tid  = threadIdx.x;
    const int kc   = tid & 7, lr = tid >> 3;     // P loader
    const int kb   = tid & 3, dr = tid >> 2;     // V loader
    const int wave = tid >> 6, lane = tid & 63;
    const int wr   = wave >> 1, wc = wave & 1;
    const int q    = lane >> 4, m = lane & 15;

    frag_cd zero = {0.f, 0.f, 0.f, 0.f};
    frag_cd acc[4][4];
    #pragma unroll
    for (int i = 0; i < 4; ++i)
        #pragma unroll
        for (int j = 0; j < 4; ++j) acc[i][j] = zero;

    for (int k0 = 0; k0 < S_; k0 += 32) {
        float4 ev[4]; float rml[4];
        #pragma unroll
        for (int p = 0; p < 4; ++p) {
            ev[p]  = *(const float4*)(Eb + (size_t)(r0 + lr + 32 * p) * S_ + k0 + kc * 4);
            rml[p] = rmb[r0 + lr + 32 * p];
        }
        frag_ab vv[2];
        #pragma unroll
        for (int p = 0; p < 2; ++p)
            vv[p] = *(const frag_ab*)(Vb + (size_t)(d0 + dr + 64 * p) * S_ + k0 + kb * 8);

        __syncthreads();
        #pragma unroll
        for (int p = 0; p < 4; ++p) {
            short4 pv;
            pv.x = f2bf(exp2f((ev[p].x - rml[p]) * LOG2E));
            pv.y = f2bf(exp2f((ev[p].y - rml[p]) * LOG2E));
            pv.z = f2bf(exp2f((ev[p].z - rml[p]) * LOG2E));
            pv.w = f2bf(exp2f((ev[p].w - rml[p]) * LOG2E));
            *(short4*)&Ps[lr + 32 * p][kc * 4] = pv;
        }
        #pragma unroll
        for (int p = 0; p < 2; ++p)
            *(frag_ab*)&Vs[dr + 64 * p][kb * 8] = vv[p];
        __syncthreads();

        frag_ab af[4], bfr[4];
        #pragma unroll
        for (int t = 0; t < 4; ++t) {
            af[t]  = *(const frag_ab*)&Ps[wr * 64 + t * 16 + m][q * 8];
            bfr[t] = *(const frag_ab*)&Vs[wc * 64 + t * 16 + m][q * 8];
        }
        #pragma unroll
        for (int mt = 0; mt < 4; ++mt)
            #pragma unroll
            for (int nt = 0; nt < 4; ++nt)
                acc[mt][nt] = __builtin_amdgcn_mfma_f32_16x16x32_bf16(af[mt], bfr[nt], acc[mt][nt], 0, 0, 0);
    }

    #pragma unroll
    for (int mt = 0; mt < 4; ++mt)
        #pragma unroll
        for (int nt = 0; nt < 4; ++nt) {
            const int rb  = r0 + wr * 64 + mt * 16 + q * 4;
            const int col = d0 + wc * 64 + nt * 16 + m;
            #pragma unroll
            for (int r = 0; r < 4; ++r) {
                const int row = rb + r;
                const float s  = rib[row];
                const float at = acc[mt][nt][r] * s;
                const float xv = Xb[(size_t)row * S_ + col];
                float* o = Ob + (size_t)row * 2048 + col;
                o[0]    = xv;
                o[512]  = at;
                o[1024] = xv - at;
                o[1536] = xv * at;
            }
        }
}

// ---------------------------------------------------------------------------
extern "C" void kernel_launch(void* const* d_in, const int* in_sizes, int n_in,
                              void* d_out, int out_size, void* d_ws, size_t ws_size,
                              hipStream_t stream)
{
    const float* A  = (const float*)d_in[0];   // a_bar [32,512,512]
    const float* Bm = (const float*)d_in[1];   // b_bar [32,512,512]
    float* Ma = (float*)d_out;                             // [32,512,2048]
    float* Mb = Ma + (size_t)B_ * S_ * 2048;               // [32,512,2048]

    // ws layout: E fp32, Et fp32, At bf16, Bt bf16, 4 stat vectors
    float* E    = (float*)d_ws;
    float* Et   = E + (size_t)B_ * SxS;
    short* At   = (short*)(Et + (size_t)B_ * SxS);
    short* Bt   = At + (size_t)B_ * SxS;
    float* rmax = (float*)(Bt + (size_t)B_ * SxS);
    float* rinv = rmax + B_ * S_;
    float* cmax = rinv + B_ * S_;
    float* cinv = cmax + B_ * S_;

    k_trans   <<<dim3(8, 8, 64),    256, 0, stream>>>(A, Bm, At, Bt);
    k_gemm_e  <<<dim3(4, 4, B_),    256, 0, stream>>>(A, Bm, E, Et);
    k_rowstats<<<dim3(B_ * S_ / 4), 256, 0, stream>>>(E,  rmax, rinv);
    k_rowstats<<<dim3(B_ * S_ / 4), 256, 0, stream>>>(Et, cmax, cinv);
    k_pv      <<<dim3(4, 4, B_),    256, 0, stream>>>(E,  rmax, rinv, Bt, A,  Ma);
    k_pv      <<<dim3(4, 4, B_),    256, 0, stream>>>(Et, cmax, cinv, At, Bm, Mb);
}